// Round 1
// baseline (2079.039 us; speedup 1.0000x reference)
//
#include <hip/hip_runtime.h>

#define NEG_SLOPE 0.2f

__device__ __forceinline__ float elu1(float v) { return v > 0.f ? v : expm1f(v); }
__device__ __forceinline__ float lrelu(float v) { return v > 0.f ? v : NEG_SLOPE * v; }

// K1: h1 = x @ W1  (N x 5 -> N x 128), plus per-head attention dots a_src1/a_dst1
__global__ __launch_bounds__(256) void k_feat1(
    const float* __restrict__ x, const float* __restrict__ W1,
    const float* __restrict__ att_s, const float* __restrict__ att_d,
    float* __restrict__ h1, float* __restrict__ a_s, float* __restrict__ a_d, int N) {
    __shared__ float Wl[5 * 128];
    for (int i = threadIdx.x; i < 5 * 128; i += blockDim.x) Wl[i] = W1[i];
    __syncthreads();
    int t = blockIdx.x * blockDim.x + threadIdx.x;
    int n = t >> 7, c = t & 127;
    if (n >= N) return;
    const float* xr = x + (size_t)n * 5;
    float h = 0.f;
#pragma unroll
    for (int k = 0; k < 5; ++k) h = fmaf(xr[k], Wl[k * 128 + c], h);
    h1[(size_t)n * 128 + c] = h;
    float as = h * att_s[c], ad = h * att_d[c];
#pragma unroll
    for (int m = 16; m; m >>= 1) {
        as += __shfl_xor(as, m, 32);
        ad += __shfl_xor(ad, m, 32);
    }
    if ((c & 31) == 0) {
        a_s[n * 4 + (c >> 5)] = as;
        a_d[n * 4 + (c >> 5)] = ad;
    }
}

// K2: per-edge logits -> exp, accumulate softmax denominator per (dst, head)
__global__ __launch_bounds__(256) void k_edge_sm1(
    const int* __restrict__ ei, int E, int ET,
    const float* __restrict__ a_s, const float* __restrict__ a_d,
    float* __restrict__ ex, float* __restrict__ denom) {
    int e = blockIdx.x * blockDim.x + threadIdx.x;
    if (e >= ET) return;
    int s, d;
    if (e < E) { s = ei[e]; d = ei[E + e]; } else { s = d = e - E; }
    const float4 as = *(const float4*)(a_s + (size_t)s * 4);
    const float4 ad = *(const float4*)(a_d + (size_t)d * 4);
    float4 v;
    v.x = expf(lrelu(as.x + ad.x));
    v.y = expf(lrelu(as.y + ad.y));
    v.z = expf(lrelu(as.z + ad.z));
    v.w = expf(lrelu(as.w + ad.w));
    *(float4*)(ex + (size_t)e * 4) = v;
    atomicAdd(denom + (size_t)d * 4 + 0, v.x);
    atomicAdd(denom + (size_t)d * 4 + 1, v.y);
    atomicAdd(denom + (size_t)d * 4 + 2, v.z);
    atomicAdd(denom + (size_t)d * 4 + 3, v.w);
}

// K3: scatter alpha * h1[src] into out1[dst]  (32 threads/edge, 4 channels each)
__global__ __launch_bounds__(256) void k_scatter1(
    const int* __restrict__ ei, int E, int ET,
    const float* __restrict__ ex, const float* __restrict__ denom,
    const float* __restrict__ h1, float* __restrict__ out1) {
    int t = blockIdx.x * blockDim.x + threadIdx.x;
    int e = t >> 5;
    if (e >= ET) return;
    int q = t & 31, hh = q >> 3;
    int s, d;
    if (e < E) { s = ei[e]; d = ei[E + e]; } else { s = d = e - E; }
    float alpha = ex[(size_t)e * 4 + hh] / denom[(size_t)d * 4 + hh];
    float4 hv = *(const float4*)(h1 + (size_t)s * 128 + q * 4);
    float* o = out1 + (size_t)d * 128 + q * 4;
    atomicAdd(o + 0, alpha * hv.x);
    atomicAdd(o + 1, alpha * hv.y);
    atomicAdd(o + 2, alpha * hv.z);
    atomicAdd(o + 3, alpha * hv.w);
}

// K4: in-place bias + ELU
__global__ __launch_bounds__(256) void k_bias_elu(
    float* __restrict__ buf, const float* __restrict__ b, int total, int cmask) {
    int t = blockIdx.x * blockDim.x + threadIdx.x;
    if (t >= total) return;
    float v = buf[t] + b[t & cmask];
    buf[t] = elu1(v);
}

// K5: h2 = h1b @ W2 (128 -> 32), plus a_src2/a_dst2 (1 head)
__global__ __launch_bounds__(256) void k_feat2(
    const float* __restrict__ h1b, const float* __restrict__ W2,
    const float* __restrict__ att_s, const float* __restrict__ att_d,
    float* __restrict__ h2, float* __restrict__ a_s, float* __restrict__ a_d, int N) {
    __shared__ float Wl[128 * 32];
    for (int i = threadIdx.x; i < 128 * 32; i += blockDim.x) Wl[i] = W2[i];
    __syncthreads();
    int t = blockIdx.x * blockDim.x + threadIdx.x;
    int n = t >> 5, c = t & 31;
    if (n >= N) return;
    const float4* hr4 = (const float4*)(h1b + (size_t)n * 128);
    float acc = 0.f;
#pragma unroll
    for (int k4 = 0; k4 < 32; ++k4) {
        float4 hv = hr4[k4];
        acc = fmaf(hv.x, Wl[(k4 * 4 + 0) * 32 + c], acc);
        acc = fmaf(hv.y, Wl[(k4 * 4 + 1) * 32 + c], acc);
        acc = fmaf(hv.z, Wl[(k4 * 4 + 2) * 32 + c], acc);
        acc = fmaf(hv.w, Wl[(k4 * 4 + 3) * 32 + c], acc);
    }
    h2[(size_t)n * 32 + c] = acc;
    float as = acc * att_s[c], ad = acc * att_d[c];
#pragma unroll
    for (int m = 16; m; m >>= 1) {
        as += __shfl_xor(as, m, 32);
        ad += __shfl_xor(ad, m, 32);
    }
    if (c == 0) { a_s[n] = as; a_d[n] = ad; }
}

// K6: layer-2 edge softmax numerator/denominator (1 head)
__global__ __launch_bounds__(256) void k_edge_sm2(
    const int* __restrict__ ei, int E, int ET,
    const float* __restrict__ a_s, const float* __restrict__ a_d,
    float* __restrict__ ex, float* __restrict__ denom) {
    int e = blockIdx.x * blockDim.x + threadIdx.x;
    if (e >= ET) return;
    int s, d;
    if (e < E) { s = ei[e]; d = ei[E + e]; } else { s = d = e - E; }
    float v = expf(lrelu(a_s[s] + a_d[d]));
    ex[e] = v;
    atomicAdd(denom + d, v);
}

// K7: scatter alpha * h2[src] into out2[dst]  (8 threads/edge, 4 channels each)
__global__ __launch_bounds__(256) void k_scatter2(
    const int* __restrict__ ei, int E, int ET,
    const float* __restrict__ ex, const float* __restrict__ denom,
    const float* __restrict__ h2, float* __restrict__ out2) {
    int t = blockIdx.x * blockDim.x + threadIdx.x;
    int e = t >> 3;
    if (e >= ET) return;
    int q = t & 7;
    int s, d;
    if (e < E) { s = ei[e]; d = ei[E + e]; } else { s = d = e - E; }
    float alpha = ex[e] / denom[d];
    float4 hv = *(const float4*)(h2 + (size_t)s * 32 + q * 4);
    float* o = out2 + (size_t)d * 32 + q * 4;
    atomicAdd(o + 0, alpha * hv.x);
    atomicAdd(o + 1, alpha * hv.y);
    atomicAdd(o + 2, alpha * hv.z);
    atomicAdd(o + 3, alpha * hv.w);
}

// K8: bias + ELU + MLP head: relu(z @ Wc1 + bc1) @ Wc2 + bc2
__global__ __launch_bounds__(256) void k_head(
    const float* __restrict__ out2, const float* __restrict__ b2,
    const float* __restrict__ Wc1, const float* __restrict__ bc1,
    const float* __restrict__ Wc2, const float* __restrict__ bc2,
    float* __restrict__ out, int N) {
    __shared__ float Wl[32 * 16];
    __shared__ float b1l[16], w2l[16];
    for (int i = threadIdx.x; i < 512; i += blockDim.x) Wl[i] = Wc1[i];
    if (threadIdx.x < 16) {
        b1l[threadIdx.x] = bc1[threadIdx.x];
        w2l[threadIdx.x] = Wc2[threadIdx.x];
    }
    __syncthreads();
    int n = blockIdx.x * blockDim.x + threadIdx.x;
    if (n >= N) return;
    float z[32];
#pragma unroll
    for (int c = 0; c < 32; ++c) z[c] = elu1(out2[(size_t)n * 32 + c] + b2[c]);
    float acc = bc2[0];
#pragma unroll
    for (int j = 0; j < 16; ++j) {
        float y = b1l[j];
#pragma unroll
        for (int c = 0; c < 32; ++c) y = fmaf(z[c], Wl[c * 16 + j], y);
        acc = fmaf(fmaxf(y, 0.f), w2l[j], acc);
    }
    out[n] = acc;
}

extern "C" void kernel_launch(void* const* d_in, const int* in_sizes, int n_in,
                              void* d_out, int out_size, void* d_ws, size_t ws_size,
                              hipStream_t stream) {
    const float* x   = (const float*)d_in[0];
    const int*   ei  = (const int*)d_in[1];
    const float* W1  = (const float*)d_in[2];
    const float* as1 = (const float*)d_in[3];
    const float* ad1 = (const float*)d_in[4];
    const float* b1  = (const float*)d_in[5];
    const float* W2  = (const float*)d_in[6];
    const float* as2 = (const float*)d_in[7];
    const float* ad2 = (const float*)d_in[8];
    const float* b2  = (const float*)d_in[9];
    const float* Wc1 = (const float*)d_in[10];
    const float* bc1 = (const float*)d_in[11];
    const float* Wc2 = (const float*)d_in[12];
    const float* bc2 = (const float*)d_in[13];
    float* out = (float*)d_out;

    const int N = out_size;          // 50000
    const int E = in_sizes[1] / 2;   // 800000
    const int ET = E + N;            // + self loops

    // Workspace layout (floats). Layer-2 buffers alias the h1 region (h1 is
    // dead after k_scatter1). ex2 aliases ex1 (dead after k_scatter1).
    float* ws   = (float*)d_ws;
    float* h1   = ws;                           // N*128
    float* out1 = h1   + (size_t)N * 128;       // N*128 (becomes h1b in-place)
    float* a_s1 = out1 + (size_t)N * 128;       // N*4
    float* a_d1 = a_s1 + (size_t)N * 4;         // N*4
    float* den1 = a_d1 + (size_t)N * 4;         // N*4
    float* ex1  = den1 + (size_t)N * 4;         // ET*4
    float* h2   = h1;                           // N*32   (aliases h1)
    float* out2 = h1 + (size_t)N * 32;          // N*32   (aliases h1)
    float* a_s2 = h1 + (size_t)N * 64;          // N      (aliases h1)
    float* a_d2 = a_s2 + N;                     // N
    float* den2 = a_d2 + N;                     // N
    float* ex2  = ex1;                          // ET     (aliases ex1)

    auto cdiv = [](long long a, long long b) { return (int)((a + b - 1) / b); };
    const int B = 256;

    // ---- layer 1 ----
    hipMemsetAsync(out1, 0, (size_t)N * 128 * sizeof(float), stream);
    hipMemsetAsync(den1, 0, (size_t)N * 4 * sizeof(float), stream);

    k_feat1<<<cdiv((long long)N * 128, B), B, 0, stream>>>(x, W1, as1, ad1, h1, a_s1, a_d1, N);
    k_edge_sm1<<<cdiv(ET, B), B, 0, stream>>>(ei, E, ET, a_s1, a_d1, ex1, den1);
    k_scatter1<<<cdiv((long long)ET * 32, B), B, 0, stream>>>(ei, E, ET, ex1, den1, h1, out1);
    k_bias_elu<<<cdiv((long long)N * 128, B), B, 0, stream>>>(out1, b1, N * 128, 127);

    // ---- layer 2 (h1 region now reusable) ----
    hipMemsetAsync(out2, 0, (size_t)N * 32 * sizeof(float), stream);
    hipMemsetAsync(den2, 0, (size_t)N * sizeof(float), stream);

    k_feat2<<<cdiv((long long)N * 32, B), B, 0, stream>>>(out1, W2, as2, ad2, h2, a_s2, a_d2, N);
    k_edge_sm2<<<cdiv(ET, B), B, 0, stream>>>(ei, E, ET, a_s2, a_d2, ex2, den2);
    k_scatter2<<<cdiv((long long)ET * 8, B), B, 0, stream>>>(ei, E, ET, ex2, den2, h2, out2);

    // ---- classifier head ----
    k_head<<<cdiv(N, B), B, 0, stream>>>(out2, b2, Wc1, bc1, Wc2, bc2, out, N);
}

// Round 2
// 370.807 us; speedup vs baseline: 5.6068x; 5.6068x over previous
//
#include <hip/hip_runtime.h>

#define NEG_SLOPE 0.2f

__device__ __forceinline__ float elu1(float v) { return v > 0.f ? v : expm1f(v); }
__device__ __forceinline__ float lrelu(float v) { return v > 0.f ? v : NEG_SLOPE * v; }

// ---------------- CSR build ----------------

// degree histogram over dst
__global__ __launch_bounds__(256) void k_deg(
    const int* __restrict__ ei, int E, int ET, int* __restrict__ deg) {
    int e = blockIdx.x * blockDim.x + threadIdx.x;
    if (e >= ET) return;
    int d = (e < E) ? ei[E + e] : e - E;
    atomicAdd(deg + d, 1);
}

// single-block exclusive scan: off[0]=0, off[i+1]=off[i]+deg[i]; cur[i]=off[i]
__global__ __launch_bounds__(1024) void k_scan(
    const int* __restrict__ deg, int* __restrict__ off, int* __restrict__ cur, int N) {
    __shared__ int wsum[16];
    __shared__ int carry_s;
    int lane = threadIdx.x & 63;
    int w = threadIdx.x >> 6;
    if (threadIdx.x == 0) { carry_s = 0; off[0] = 0; cur[0] = 0; }
    __syncthreads();
    for (int base = 0; base < N; base += 1024) {
        int i = base + threadIdx.x;
        int v = (i < N) ? deg[i] : 0;
        int sc = v;
#pragma unroll
        for (int m = 1; m < 64; m <<= 1) {
            int t = __shfl_up(sc, m, 64);
            if (lane >= m) sc += t;
        }
        if (lane == 63) wsum[w] = sc;
        __syncthreads();
        if (w == 0 && lane < 16) {
            int s2 = wsum[lane];
#pragma unroll
            for (int m = 1; m < 16; m <<= 1) {
                int u = __shfl_up(s2, m, 64);
                if (lane >= m) s2 += u;
            }
            wsum[lane] = s2;
        }
        __syncthreads();
        int carry = carry_s;
        int waveoff = (w == 0) ? 0 : wsum[w - 1];
        int inc = carry + waveoff + sc;   // inclusive scan of deg[0..i]
        if (i < N) {
            off[i + 1] = inc;
            if (i + 1 < N) cur[i + 1] = inc;
        }
        __syncthreads();
        if (threadIdx.x == 1023) carry_s = carry + wsum[15];
        __syncthreads();
    }
}

// scatter edge srcs into CSR slots
__global__ __launch_bounds__(256) void k_fill(
    const int* __restrict__ ei, int E, int ET,
    int* __restrict__ cur, int* __restrict__ csr_src) {
    int e = blockIdx.x * blockDim.x + threadIdx.x;
    if (e >= ET) return;
    int s, d;
    if (e < E) { s = ei[e]; d = ei[E + e]; } else { s = d = e - E; }
    int p = atomicAdd(cur + d, 1);
    csr_src[p] = s;
}

// ---------------- layer compute ----------------

// h1 = x @ W1  (N x 5 -> N x 128), plus per-head attention dots
__global__ __launch_bounds__(256) void k_feat1(
    const float* __restrict__ x, const float* __restrict__ W1,
    const float* __restrict__ att_s, const float* __restrict__ att_d,
    float* __restrict__ h1, float* __restrict__ a_s, float* __restrict__ a_d, int N) {
    __shared__ float Wl[5 * 128];
    for (int i = threadIdx.x; i < 5 * 128; i += blockDim.x) Wl[i] = W1[i];
    __syncthreads();
    int t = blockIdx.x * blockDim.x + threadIdx.x;
    int n = t >> 7, c = t & 127;
    if (n >= N) return;
    const float* xr = x + (size_t)n * 5;
    float h = 0.f;
#pragma unroll
    for (int k = 0; k < 5; ++k) h = fmaf(xr[k], Wl[k * 128 + c], h);
    h1[(size_t)n * 128 + c] = h;
    float as = h * att_s[c], ad = h * att_d[c];
#pragma unroll
    for (int m = 16; m; m >>= 1) {
        as += __shfl_xor(as, m, 32);
        ad += __shfl_xor(ad, m, 32);
    }
    if ((c & 31) == 0) {
        a_s[n * 4 + (c >> 5)] = as;
        a_d[n * 4 + (c >> 5)] = ad;
    }
}

// layer-1 aggregation: one 64-lane wave per dst node, 2 channels/lane.
// loop 1 (lane-parallel over edges): ex[p] = exp(lrelu(a_s[s]+a_d[d])), wave-reduce denom
// loop 2 (channel-parallel): acc += ex * h1[src]; epilogue: /denom + bias + ELU
__global__ __launch_bounds__(256) void k_agg1(
    const int* __restrict__ off, const int* __restrict__ csr_src,
    const float* __restrict__ a_s, const float* __restrict__ a_d,
    const float* __restrict__ h1, float* __restrict__ ex,
    const float* __restrict__ b1, float* __restrict__ out1, int N) {
    int wid = (blockIdx.x * blockDim.x + threadIdx.x) >> 6;
    int lane = threadIdx.x & 63;
    if (wid >= N) return;
    int d = wid;
    int p0 = off[d], p1 = off[d + 1];
    float4 ad4 = *(const float4*)(a_d + (size_t)d * 4);
    float dx = 0.f, dy = 0.f, dz = 0.f, dw = 0.f;
    for (int p = p0 + lane; p < p1; p += 64) {
        int s = csr_src[p];
        float4 as4 = *(const float4*)(a_s + (size_t)s * 4);
        float4 v;
        v.x = expf(lrelu(as4.x + ad4.x));
        v.y = expf(lrelu(as4.y + ad4.y));
        v.z = expf(lrelu(as4.z + ad4.z));
        v.w = expf(lrelu(as4.w + ad4.w));
        *(float4*)(ex + (size_t)p * 4) = v;
        dx += v.x; dy += v.y; dz += v.z; dw += v.w;
    }
#pragma unroll
    for (int m = 32; m; m >>= 1) {
        dx += __shfl_xor(dx, m);
        dy += __shfl_xor(dy, m);
        dz += __shfl_xor(dz, m);
        dw += __shfl_xor(dw, m);
    }
    int c0 = lane * 2;
    int hh = c0 >> 5;                 // head index (both channels same head)
    float accx = 0.f, accy = 0.f;
    for (int p = p0; p < p1; ++p) {
        int s = csr_src[p];
        float exh = ex[(size_t)p * 4 + hh];
        float2 hv = *(const float2*)(h1 + (size_t)s * 128 + c0);
        accx = fmaf(exh, hv.x, accx);
        accy = fmaf(exh, hv.y, accy);
    }
    float dh = (hh == 0) ? dx : (hh == 1) ? dy : (hh == 2) ? dz : dw;
    float inv = 1.f / dh;             // self-loop guarantees nonempty segment
    out1[(size_t)d * 128 + c0]     = elu1(fmaf(accx, inv, b1[c0]));
    out1[(size_t)d * 128 + c0 + 1] = elu1(fmaf(accy, inv, b1[c0 + 1]));
}

// h2 = h1b @ W2 (128 -> 32), plus single-head attention dots
__global__ __launch_bounds__(256) void k_feat2(
    const float* __restrict__ h1b, const float* __restrict__ W2,
    const float* __restrict__ att_s, const float* __restrict__ att_d,
    float* __restrict__ h2, float* __restrict__ a_s, float* __restrict__ a_d, int N) {
    __shared__ float Wl[128 * 32];
    for (int i = threadIdx.x; i < 128 * 32; i += blockDim.x) Wl[i] = W2[i];
    __syncthreads();
    int t = blockIdx.x * blockDim.x + threadIdx.x;
    int n = t >> 5, c = t & 31;
    if (n >= N) return;
    const float4* hr4 = (const float4*)(h1b + (size_t)n * 128);
    float acc = 0.f;
#pragma unroll
    for (int k4 = 0; k4 < 32; ++k4) {
        float4 hv = hr4[k4];
        acc = fmaf(hv.x, Wl[(k4 * 4 + 0) * 32 + c], acc);
        acc = fmaf(hv.y, Wl[(k4 * 4 + 1) * 32 + c], acc);
        acc = fmaf(hv.z, Wl[(k4 * 4 + 2) * 32 + c], acc);
        acc = fmaf(hv.w, Wl[(k4 * 4 + 3) * 32 + c], acc);
    }
    h2[(size_t)n * 32 + c] = acc;
    float as = acc * att_s[c], ad = acc * att_d[c];
#pragma unroll
    for (int m = 16; m; m >>= 1) {
        as += __shfl_xor(as, m, 32);
        ad += __shfl_xor(ad, m, 32);
    }
    if (c == 0) { a_s[n] = as; a_d[n] = ad; }
}

// layer-2 aggregation: 32-lane group per dst node, 1 channel/lane
__global__ __launch_bounds__(256) void k_agg2(
    const int* __restrict__ off, const int* __restrict__ csr_src,
    const float* __restrict__ a_s, const float* __restrict__ a_d,
    const float* __restrict__ h2, float* __restrict__ ex,
    const float* __restrict__ b2, float* __restrict__ out2, int N) {
    int g = (blockIdx.x * blockDim.x + threadIdx.x) >> 5;
    int lane = threadIdx.x & 31;
    if (g >= N) return;
    int d = g;
    int p0 = off[d], p1 = off[d + 1];
    float ad = a_d[d];
    float den = 0.f;
    for (int p = p0 + lane; p < p1; p += 32) {
        int s = csr_src[p];
        float v = expf(lrelu(a_s[s] + ad));
        ex[p] = v;
        den += v;
    }
#pragma unroll
    for (int m = 16; m; m >>= 1) den += __shfl_xor(den, m, 32);
    float acc = 0.f;
    for (int p = p0; p < p1; ++p) {
        int s = csr_src[p];
        acc = fmaf(ex[p], h2[(size_t)s * 32 + lane], acc);
    }
    out2[(size_t)d * 32 + lane] = elu1(fmaf(acc, 1.f / den, b2[lane]));
}

// classifier head: relu(z @ Wc1 + bc1) @ Wc2 + bc2
__global__ __launch_bounds__(256) void k_head(
    const float* __restrict__ out2,
    const float* __restrict__ Wc1, const float* __restrict__ bc1,
    const float* __restrict__ Wc2, const float* __restrict__ bc2,
    float* __restrict__ out, int N) {
    __shared__ float Wl[32 * 16];
    __shared__ float b1l[16], w2l[16];
    for (int i = threadIdx.x; i < 512; i += blockDim.x) Wl[i] = Wc1[i];
    if (threadIdx.x < 16) {
        b1l[threadIdx.x] = bc1[threadIdx.x];
        w2l[threadIdx.x] = Wc2[threadIdx.x];
    }
    __syncthreads();
    int n = blockIdx.x * blockDim.x + threadIdx.x;
    if (n >= N) return;
    float z[32];
#pragma unroll
    for (int c = 0; c < 32; ++c) z[c] = out2[(size_t)n * 32 + c];
    float acc = bc2[0];
#pragma unroll
    for (int j = 0; j < 16; ++j) {
        float y = b1l[j];
#pragma unroll
        for (int c = 0; c < 32; ++c) y = fmaf(z[c], Wl[c * 16 + j], y);
        acc = fmaf(fmaxf(y, 0.f), w2l[j], acc);
    }
    out[n] = acc;
}

extern "C" void kernel_launch(void* const* d_in, const int* in_sizes, int n_in,
                              void* d_out, int out_size, void* d_ws, size_t ws_size,
                              hipStream_t stream) {
    const float* x   = (const float*)d_in[0];
    const int*   ei  = (const int*)d_in[1];
    const float* W1  = (const float*)d_in[2];
    const float* as1 = (const float*)d_in[3];
    const float* ad1 = (const float*)d_in[4];
    const float* b1  = (const float*)d_in[5];
    const float* W2  = (const float*)d_in[6];
    const float* as2 = (const float*)d_in[7];
    const float* ad2 = (const float*)d_in[8];
    const float* b2  = (const float*)d_in[9];
    const float* Wc1 = (const float*)d_in[10];
    const float* bc1 = (const float*)d_in[11];
    const float* Wc2 = (const float*)d_in[12];
    const float* bc2 = (const float*)d_in[13];
    float* out = (float*)d_out;

    const int N = out_size;          // 50000
    const int E = in_sizes[1] / 2;   // 800000
    const int ET = E + N;            // + self loops

    // Workspace layout (floats then ints).
    float* ws    = (float*)d_ws;
    float* h1    = ws;                              // N*128
    float* out1  = h1   + (size_t)N * 128;          // N*128 (= h1b after agg1)
    float* a_s1  = out1 + (size_t)N * 128;          // N*4
    float* a_d1  = a_s1 + (size_t)N * 4;            // N*4
    float* ex    = a_d1 + (size_t)N * 4;            // ET*4 (layer2 aliases front)
    int*   off   = (int*)(ex + (size_t)ET * 4);     // N+1
    int*   cur   = off + (N + 1);                   // N
    int*   deg   = cur + N;                         // N
    int*   csr_src = deg + N;                       // ET
    // layer-2 aliases (h1 dead after k_agg1)
    float* h2    = h1;                              // N*32
    float* out2  = h1 + (size_t)N * 32;             // N*32
    float* a_s2  = h1 + (size_t)N * 64;             // N
    float* a_d2  = a_s2 + N;                        // N

    auto cdiv = [](long long a, long long b) { return (int)((a + b - 1) / b); };
    const int B = 256;

    // ---- CSR build (shared by both layers) ----
    hipMemsetAsync(deg, 0, (size_t)N * sizeof(int), stream);
    k_deg<<<cdiv(ET, B), B, 0, stream>>>(ei, E, ET, deg);
    k_scan<<<1, 1024, 0, stream>>>(deg, off, cur, N);
    k_fill<<<cdiv(ET, B), B, 0, stream>>>(ei, E, ET, cur, csr_src);

    // ---- layer 1 ----
    k_feat1<<<cdiv((long long)N * 128, B), B, 0, stream>>>(x, W1, as1, ad1, h1, a_s1, a_d1, N);
    k_agg1<<<cdiv((long long)N * 64, B), B, 0, stream>>>(off, csr_src, a_s1, a_d1, h1, ex, b1, out1, N);

    // ---- layer 2 ----
    k_feat2<<<cdiv((long long)N * 32, B), B, 0, stream>>>(out1, W2, as2, ad2, h2, a_s2, a_d2, N);
    k_agg2<<<cdiv((long long)N * 32, B), B, 0, stream>>>(off, csr_src, a_s2, a_d2, h2, ex, b2, out2, N);

    // ---- classifier head ----
    k_head<<<cdiv(N, B), B, 0, stream>>>(out2, Wc1, bc1, Wc2, bc2, out, N);
}

// Round 3
// 220.274 us; speedup vs baseline: 9.4384x; 1.6834x over previous
//
#include <hip/hip_runtime.h>

#define NEG_SLOPE 0.2f

__device__ __forceinline__ float elu1(float v) { return v > 0.f ? v : expm1f(v); }
__device__ __forceinline__ float lrelu(float v) { return v > 0.f ? v : NEG_SLOPE * v; }

// ---------------- CSR build ----------------

__global__ __launch_bounds__(256) void k_deg(
    const int* __restrict__ ei, int E, int ET, int* __restrict__ deg) {
    int e = blockIdx.x * blockDim.x + threadIdx.x;
    if (e >= ET) return;
    int d = (e < E) ? ei[E + e] : e - E;
    atomicAdd(deg + d, 1);
}

// per-block inclusive scan of deg -> off[i+1] (partial), block totals -> bsum
__global__ __launch_bounds__(256) void k_scan1(
    const int* __restrict__ deg, int* __restrict__ off, int* __restrict__ bsum, int N) {
    __shared__ int ws4[4], wsoff[4];
    int i = blockIdx.x * 256 + threadIdx.x;
    int lane = threadIdx.x & 63, w = threadIdx.x >> 6;
    int v = (i < N) ? deg[i] : 0;
    int sc = v;
#pragma unroll
    for (int m = 1; m < 64; m <<= 1) {
        int t = __shfl_up(sc, m, 64);
        if (lane >= m) sc += t;
    }
    if (lane == 63) ws4[w] = sc;
    __syncthreads();
    if (threadIdx.x == 0) {
        int r = 0;
#pragma unroll
        for (int j = 0; j < 4; ++j) { wsoff[j] = r; r += ws4[j]; }
        bsum[blockIdx.x] = r;
    }
    __syncthreads();
    if (i < N) off[i + 1] = sc + wsoff[w];
}

// scan block totals (nb <= 256)
__global__ __launch_bounds__(256) void k_scan2(int* __restrict__ bsum, int nb) {
    __shared__ int ws4[4], wsoff[4];
    int i = threadIdx.x;
    int lane = i & 63, w = i >> 6;
    int v = (i < nb) ? bsum[i] : 0;
    int sc = v;
#pragma unroll
    for (int m = 1; m < 64; m <<= 1) {
        int t = __shfl_up(sc, m, 64);
        if (lane >= m) sc += t;
    }
    if (lane == 63) ws4[w] = sc;
    __syncthreads();
    if (i == 0) {
        int r = 0;
#pragma unroll
        for (int j = 0; j < 4; ++j) { wsoff[j] = r; r += ws4[j]; }
    }
    __syncthreads();
    if (i < nb) bsum[i] = sc + wsoff[w];
}

// add block offsets; produce final off and cur
__global__ __launch_bounds__(256) void k_scan3(
    int* __restrict__ off, int* __restrict__ cur, const int* __restrict__ bsum, int N) {
    int i = blockIdx.x * 256 + threadIdx.x;
    if (i >= N) return;
    int add = (blockIdx.x > 0) ? bsum[blockIdx.x - 1] : 0;
    int v = off[i + 1] + add;
    off[i + 1] = v;
    if (i + 1 < N) cur[i + 1] = v;
    if (i == 0) { off[0] = 0; cur[0] = 0; }
}

__global__ __launch_bounds__(256) void k_fill(
    const int* __restrict__ ei, int E, int ET,
    int* __restrict__ cur, int* __restrict__ csr_src) {
    int e = blockIdx.x * blockDim.x + threadIdx.x;
    if (e >= ET) return;
    int s, d;
    if (e < E) { s = ei[e]; d = ei[E + e]; } else { s = d = e - E; }
    int p = atomicAdd(cur + d, 1);
    csr_src[p] = s;
}

// ---------------- layer 1 (aggregate in 5-dim input space) ----------------

// per node: pack x into padded x8, compute a_src1/a_dst1 = x @ (W1 . att)  (5x4 mats)
__global__ __launch_bounds__(256) void k_attn1(
    const float* __restrict__ x, const float* __restrict__ W1,
    const float* __restrict__ att_s, const float* __restrict__ att_d,
    float* __restrict__ x8, float4* __restrict__ as4, float4* __restrict__ ad4, int N) {
    __shared__ float Ps[5][4], Pd[5][4];
    if (threadIdx.x < 40) {
        int pair = threadIdx.x & 1, idx = threadIdx.x >> 1;   // idx in [0,20)
        int k = idx >> 2, h = idx & 3;
        const float* att = pair ? att_d : att_s;
        float r = 0.f;
#pragma unroll
        for (int c = 0; c < 32; ++c) r = fmaf(W1[k * 128 + h * 32 + c], att[h * 32 + c], r);
        if (pair) Pd[k][h] = r; else Ps[k][h] = r;
    }
    __syncthreads();
    int n = blockIdx.x * 256 + threadIdx.x;
    if (n >= N) return;
    float xv[5];
#pragma unroll
    for (int k = 0; k < 5; ++k) xv[k] = x[(size_t)n * 5 + k];
#pragma unroll
    for (int k = 0; k < 5; ++k) x8[(size_t)n * 8 + k] = xv[k];
    float s0 = 0, s1 = 0, s2 = 0, s3 = 0, d0 = 0, d1 = 0, d2 = 0, d3 = 0;
#pragma unroll
    for (int k = 0; k < 5; ++k) {
        s0 = fmaf(xv[k], Ps[k][0], s0); s1 = fmaf(xv[k], Ps[k][1], s1);
        s2 = fmaf(xv[k], Ps[k][2], s2); s3 = fmaf(xv[k], Ps[k][3], s3);
        d0 = fmaf(xv[k], Pd[k][0], d0); d1 = fmaf(xv[k], Pd[k][1], d1);
        d2 = fmaf(xv[k], Pd[k][2], d2); d3 = fmaf(xv[k], Pd[k][3], d3);
    }
    as4[n] = make_float4(s0, s1, s2, s3);
    ad4[n] = make_float4(d0, d1, d2, d3);
}

// 16-lane group per dst: single-pass softmax-weighted aggregation of x (5 dims, 4 heads)
__global__ __launch_bounds__(256) void k_agg1x(
    const int* __restrict__ off, const int* __restrict__ csr_src,
    const float4* __restrict__ as4, const float4* __restrict__ ad4,
    const float* __restrict__ x8, float* __restrict__ aggx, int N) {
    int g = (blockIdx.x * 256 + threadIdx.x) >> 4;
    int lane = threadIdx.x & 15;
    if (g >= N) return;
    int p0 = off[g], p1 = off[g + 1];
    float4 ad = ad4[g];
    float den0 = 0, den1 = 0, den2 = 0, den3 = 0;
    float acc[4][5] = {};
    for (int p = p0 + lane; p < p1; p += 16) {
        int s = csr_src[p];
        float4 as = as4[s];
        float v0 = __expf(lrelu(as.x + ad.x));
        float v1 = __expf(lrelu(as.y + ad.y));
        float v2 = __expf(lrelu(as.z + ad.z));
        float v3 = __expf(lrelu(as.w + ad.w));
        den0 += v0; den1 += v1; den2 += v2; den3 += v3;
        const float* xr = x8 + (size_t)s * 8;
        float4 xlo = *(const float4*)xr;
        float x4 = xr[4];
        float xk[5] = {xlo.x, xlo.y, xlo.z, xlo.w, x4};
#pragma unroll
        for (int k = 0; k < 5; ++k) {
            acc[0][k] = fmaf(v0, xk[k], acc[0][k]);
            acc[1][k] = fmaf(v1, xk[k], acc[1][k]);
            acc[2][k] = fmaf(v2, xk[k], acc[2][k]);
            acc[3][k] = fmaf(v3, xk[k], acc[3][k]);
        }
    }
#pragma unroll
    for (int m = 8; m; m >>= 1) {
        den0 += __shfl_xor(den0, m, 16); den1 += __shfl_xor(den1, m, 16);
        den2 += __shfl_xor(den2, m, 16); den3 += __shfl_xor(den3, m, 16);
#pragma unroll
        for (int h = 0; h < 4; ++h)
#pragma unroll
            for (int k = 0; k < 5; ++k) acc[h][k] += __shfl_xor(acc[h][k], m, 16);
    }
    if (lane == 0) {
        float i0 = 1.f / den0, i1 = 1.f / den1, i2 = 1.f / den2, i3 = 1.f / den3;
        float4* o = (float4*)(aggx + (size_t)g * 20);
        o[0] = make_float4(acc[0][0] * i0, acc[0][1] * i0, acc[0][2] * i0, acc[0][3] * i0);
        o[1] = make_float4(acc[0][4] * i0, acc[1][0] * i1, acc[1][1] * i1, acc[1][2] * i1);
        o[2] = make_float4(acc[1][3] * i1, acc[1][4] * i1, acc[2][0] * i2, acc[2][1] * i2);
        o[3] = make_float4(acc[2][2] * i2, acc[2][3] * i2, acc[2][4] * i2, acc[3][0] * i3);
        o[4] = make_float4(acc[3][1] * i3, acc[3][2] * i3, acc[3][3] * i3, acc[3][4] * i3);
    }
}

// out1 = elu(aggx @ W1 + b1)   [N,4,5] x [5,128] -> [N,128]
__global__ __launch_bounds__(256) void k_expand1(
    const float* __restrict__ aggx, const float* __restrict__ W1,
    const float* __restrict__ b1, float* __restrict__ out1, int N) {
    __shared__ float Wl[5 * 128];
    for (int i = threadIdx.x; i < 5 * 128; i += 256) Wl[i] = W1[i];
    __syncthreads();
    int t = blockIdx.x * 256 + threadIdx.x;
    int n = t >> 7, c = t & 127;
    if (n >= N) return;
    int h = c >> 5;
    const float* ag = aggx + (size_t)n * 20 + h * 5;
    float r = b1[c];
#pragma unroll
    for (int k = 0; k < 5; ++k) r = fmaf(ag[k], Wl[k * 128 + c], r);
    out1[(size_t)n * 128 + c] = elu1(r);
}

// ---------------- layer 2 ----------------

// h2 = out1 @ W2 (128 -> 32) + single-head attention dots
__global__ __launch_bounds__(256) void k_feat2(
    const float* __restrict__ h1b, const float* __restrict__ W2,
    const float* __restrict__ att_s, const float* __restrict__ att_d,
    float* __restrict__ h2, float* __restrict__ a_s, float* __restrict__ a_d, int N) {
    __shared__ float Wl[128 * 32];
    for (int i = threadIdx.x; i < 128 * 32; i += 256) Wl[i] = W2[i];
    __syncthreads();
    int t = blockIdx.x * 256 + threadIdx.x;
    int n = t >> 5, c = t & 31;
    if (n >= N) return;
    const float4* hr4 = (const float4*)(h1b + (size_t)n * 128);
    float acc = 0.f;
#pragma unroll
    for (int k4 = 0; k4 < 32; ++k4) {
        float4 hv = hr4[k4];
        acc = fmaf(hv.x, Wl[(k4 * 4 + 0) * 32 + c], acc);
        acc = fmaf(hv.y, Wl[(k4 * 4 + 1) * 32 + c], acc);
        acc = fmaf(hv.z, Wl[(k4 * 4 + 2) * 32 + c], acc);
        acc = fmaf(hv.w, Wl[(k4 * 4 + 3) * 32 + c], acc);
    }
    h2[(size_t)n * 32 + c] = acc;
    float as = acc * att_s[c], ad = acc * att_d[c];
#pragma unroll
    for (int m = 16; m; m >>= 1) {
        as += __shfl_xor(as, m, 32);
        ad += __shfl_xor(ad, m, 32);
    }
    if (c == 0) { a_s[n] = as; a_d[n] = ad; }
}

// 32-lane group per dst: single-pass aggregation + bias/ELU + fused MLP head
__global__ __launch_bounds__(256) void k_agg2h(
    const int* __restrict__ off, const int* __restrict__ csr_src,
    const float* __restrict__ a_s, const float* __restrict__ a_d,
    const float* __restrict__ h2, const float* __restrict__ b2,
    const float* __restrict__ Wc1, const float* __restrict__ bc1,
    const float* __restrict__ Wc2, const float* __restrict__ bc2,
    float* __restrict__ out, int N) {
    __shared__ float Wl[512];
    __shared__ float b2l[32], b1l[16], w2l[16];
    for (int i = threadIdx.x; i < 512; i += 256) Wl[i] = Wc1[i];
    if (threadIdx.x < 32) b2l[threadIdx.x] = b2[threadIdx.x];
    if (threadIdx.x < 16) {
        b1l[threadIdx.x] = bc1[threadIdx.x];
        w2l[threadIdx.x] = Wc2[threadIdx.x];
    }
    __syncthreads();
    int g = (blockIdx.x * 256 + threadIdx.x) >> 5;
    int lane = threadIdx.x & 31;
    if (g >= N) return;
    int p0 = off[g], p1 = off[g + 1];
    float ad = a_d[g];
    float acc = 0.f, den = 0.f;
    int p = p0;
    for (; p + 1 < p1; p += 2) {       // unroll-by-2: overlap the two gathers
        int s0 = csr_src[p], s1 = csr_src[p + 1];
        float e0 = a_s[s0], e1 = a_s[s1];
        float g0 = h2[(size_t)s0 * 32 + lane], g1 = h2[(size_t)s1 * 32 + lane];
        float v0 = __expf(lrelu(e0 + ad)), v1 = __expf(lrelu(e1 + ad));
        den += v0 + v1;
        acc = fmaf(v0, g0, acc);
        acc = fmaf(v1, g1, acc);
    }
    if (p < p1) {
        int s0 = csr_src[p];
        float v0 = __expf(lrelu(a_s[s0] + ad));
        den += v0;
        acc = fmaf(v0, h2[(size_t)s0 * 32 + lane], acc);
    }
    float z = elu1(fmaf(acc, 1.f / den, b2l[lane]));
    // head: y_j = relu(sum_c z_c Wc1[c,j] + bc1), out = sum_j y_j w2_j + bc2
    float y = b1l[lane & 15];
#pragma unroll
    for (int c = 0; c < 32; ++c) {
        float zc = __shfl(z, c, 32);
        y = fmaf(zc, Wl[c * 16 + (lane & 15)], y);
    }
    y = fmaxf(y, 0.f);
    float t = (lane < 16) ? y * w2l[lane] : 0.f;
#pragma unroll
    for (int m = 8; m; m >>= 1) t += __shfl_xor(t, m, 32);
    if (lane == 0) out[g] = t + bc2[0];
}

extern "C" void kernel_launch(void* const* d_in, const int* in_sizes, int n_in,
                              void* d_out, int out_size, void* d_ws, size_t ws_size,
                              hipStream_t stream) {
    const float* x   = (const float*)d_in[0];
    const int*   ei  = (const int*)d_in[1];
    const float* W1  = (const float*)d_in[2];
    const float* as1 = (const float*)d_in[3];
    const float* ad1 = (const float*)d_in[4];
    const float* b1  = (const float*)d_in[5];
    const float* W2  = (const float*)d_in[6];
    const float* as2 = (const float*)d_in[7];
    const float* ad2 = (const float*)d_in[8];
    const float* b2  = (const float*)d_in[9];
    const float* Wc1 = (const float*)d_in[10];
    const float* bc1 = (const float*)d_in[11];
    const float* Wc2 = (const float*)d_in[12];
    const float* bc2 = (const float*)d_in[13];
    float* out = (float*)d_out;

    const int N = out_size;          // 50000
    const int E = in_sizes[1] / 2;   // 800000
    const int ET = E + N;            // + self loops
    const int NB = (N + 255) / 256;  // scan blocks (196 <= 256)

    // Workspace layout
    float*  ws    = (float*)d_ws;
    float*  out1  = ws;                               // N*128
    float*  h2    = out1 + (size_t)N * 128;           // N*32
    float*  x8    = h2   + (size_t)N * 32;            // N*8
    float4* as4   = (float4*)(x8 + (size_t)N * 8);    // N float4
    float4* ad4   = as4 + N;                          // N float4
    float*  aggx  = (float*)(ad4 + N);                // N*20
    float*  a_s2  = aggx + (size_t)N * 20;            // N
    float*  a_d2  = a_s2 + N;                         // N
    int*    off   = (int*)(a_d2 + N);                 // N+1
    int*    cur   = off + (N + 1);                    // N
    int*    deg   = cur + N;                          // N
    int*    bsum  = deg + N;                          // NB
    int*    csr_src = bsum + 256;                     // ET

    auto cdiv = [](long long a, long long b) { return (int)((a + b - 1) / b); };
    const int B = 256;

    // ---- CSR build ----
    hipMemsetAsync(deg, 0, (size_t)N * sizeof(int), stream);
    k_deg<<<cdiv(ET, B), B, 0, stream>>>(ei, E, ET, deg);
    k_scan1<<<NB, B, 0, stream>>>(deg, off, bsum, N);
    k_scan2<<<1, B, 0, stream>>>(bsum, NB);
    k_scan3<<<NB, B, 0, stream>>>(off, cur, bsum, N);
    k_fill<<<cdiv(ET, B), B, 0, stream>>>(ei, E, ET, cur, csr_src);

    // ---- layer 1 (input-space aggregation) ----
    k_attn1<<<cdiv(N, B), B, 0, stream>>>(x, W1, as1, ad1, x8, as4, ad4, N);
    k_agg1x<<<cdiv((long long)N * 16, B), B, 0, stream>>>(off, csr_src, as4, ad4, x8, aggx, N);
    k_expand1<<<cdiv((long long)N * 128, B), B, 0, stream>>>(aggx, W1, b1, out1, N);

    // ---- layer 2 ----
    k_feat2<<<cdiv((long long)N * 32, B), B, 0, stream>>>(out1, W2, as2, ad2, h2, a_s2, a_d2, N);
    k_agg2h<<<cdiv((long long)N * 32, B), B, 0, stream>>>(off, csr_src, a_s2, a_d2, h2, b2,
                                                          Wc1, bc1, Wc2, bc2, out, N);
}